// Round 1
// baseline (74.832 us; speedup 1.0000x reference)
//
#include <hip/hip_runtime.h>

// Problem constants (from the reference)
#define B_   8
#define C_   8
#define L_   4096
#define F_   32
#define K_   10
#define PROC_ 20
#define STEP_ 5
#define NW_  815   // len(range(0, L-PROC-STEP+1, STEP))
// CHAN_OUT == NW_ == 815, so no zero-padding region exists in the output.

__global__ __launch_bounds__(256) void dtw_kernel(
    const float* __restrict__ x,      // (B, C, L)
    const float* __restrict__ kern,   // (F, K)
    float* __restrict__ out)          // (B, C*F, NW)
{
    __shared__ float sx[L_];

    const int blk = blockIdx.x;          // 0 .. B*C*F-1
    const int f = blk & (F_ - 1);        // fastest
    const int c = (blk >> 5) & (C_ - 1);
    const int b = blk >> 8;

    // Stage x[b][c][:] into LDS with float4 loads (4096 floats = 1024 float4)
    const float4* x4 = reinterpret_cast<const float4*>(x + ((size_t)(b * C_ + c)) * L_);
    float4* s4 = reinterpret_cast<float4*>(sx);
    #pragma unroll
    for (int i = 0; i < L_ / 4 / 256; ++i)
        s4[threadIdx.x + i * 256] = x4[threadIdx.x + i * 256];

    // Kernel taps: uniform across the block (f is from blockIdx) -> SGPRs
    float kk[K_];
    #pragma unroll
    for (int i = 0; i < K_; ++i) kk[i] = kern[f * K_ + i];

    __syncthreads();

    float* outp = out + ((size_t)b * (C_ * F_) + (c * F_ + f)) * (size_t)NW_;

    for (int w = threadIdx.x; w < NW_; w += 256) {
        const float* win = sx + w * STEP_;
        float wv[PROC_];
        #pragma unroll
        for (int j = 0; j < PROC_; ++j) wv[j] = win[j];

        float row[PROC_];
        // row0 = cumsum((kk[0]-wv)^2)
        {
            float d = kk[0] - wv[0];
            row[0] = d * d;
            #pragma unroll
            for (int j = 1; j < PROC_; ++j) {
                float dj = kk[0] - wv[j];
                row[j] = fmaf(dj, dj, row[j - 1]);
            }
        }
        // rows 1..K-1: cur = d + min(left, up, diag)
        #pragma unroll
        for (int i = 1; i < K_; ++i) {
            float diag = row[0];
            float d0 = kk[i] - wv[0];
            float cur = fmaf(d0, d0, diag);   // first = D[i][0] + prev[0]
            row[0] = cur;
            float left = cur;
            #pragma unroll
            for (int j = 1; j < PROC_; ++j) {
                float up = row[j];
                float dj = kk[i] - wv[j];
                float m = fminf(fminf(left, up), diag);  // -> v_min3_f32
                cur = fmaf(dj, dj, m);
                diag = up;
                row[j] = cur;
                left = cur;
            }
        }
        outp[w] = row[PROC_ - 1];
    }
}

extern "C" void kernel_launch(void* const* d_in, const int* in_sizes, int n_in,
                              void* d_out, int out_size, void* d_ws, size_t ws_size,
                              hipStream_t stream) {
    const float* x    = (const float*)d_in[0];   // (8, 8, 4096) fp32
    const float* kern = (const float*)d_in[1];   // (32, 10) fp32
    float* out        = (float*)d_out;           // (8, 256, 815) fp32

    dim3 grid(B_ * C_ * F_);   // 2048 blocks
    dim3 block(256);
    hipLaunchKernelGGL(dtw_kernel, grid, block, 0, stream, x, kern, out);
}